// Round 4
// baseline (20769.669 us; speedup 1.0000x reference)
//
#include <hip/hip_runtime.h>
#include <stdint.h>

// Problem constants
#define SEQ   2048
#define DE    256
#define DXX   64
#define DIN   320      // DE + DX
#define HH    256      // hidden per direction
#define G4    1024     // 4*HH
#define NT    64       // tags

// Workspace layout (float32 slot indices)
// GX [2][SEQ][G4] ; H [2][SEQ+1][HH] (slot 0 = h_{-1} = 0) ; C [2][HH] ;
// FE [SEQ][NT] ; BP u8 [SEQ][NT]
static constexpr size_t OFF_GX = 0;
static constexpr size_t OFF_H  = OFF_GX + (size_t)2 * SEQ * G4;        // 4194304
static constexpr size_t HSTR   = (size_t)(SEQ + 1) * HH;               // 524544
static constexpr size_t OFF_C  = OFF_H + 2 * HSTR;                     // 5243392
static constexpr size_t OFF_FE = OFF_C + 2 * HH;                       // 5243904
static constexpr size_t OFF_BP = OFF_FE + (size_t)SEQ * NT;            // 5374976
static constexpr size_t WS_NEEDED_BYTES = OFF_BP * 4 + (size_t)SEQ * NT; // ~21.6 MB

// ---------------------------------------------------------------------------
// K0: zero h_{-1} and c for both directions. 1 block x 256.
// ---------------------------------------------------------------------------
__global__ __launch_bounds__(256) void k_init(float* __restrict__ H,
                                              float* __restrict__ C) {
  const int tid = threadIdx.x;
  H[tid] = 0.f;              // h_{-1}, dir 0
  H[HSTR + tid] = 0.f;       // h_{-1}, dir 1
  C[tid] = 0.f;              // c, dir 0
  C[HH + tid] = 0.f;         // c, dir 1
}

// ---------------------------------------------------------------------------
// K1: fused gather + gx = x @ w_ih.T + (b_ih + b_hh), both directions.
// grid (SEQ/32, G4/256, 2), block 512.
// ---------------------------------------------------------------------------
__global__ __launch_bounds__(512) void k_gx(
    const int* __restrict__ sent, const int* __restrict__ extra,
    const float* __restrict__ emb, const float* __restrict__ xemb,
    const float* __restrict__ wf, const float* __restrict__ wb,
    const float* __restrict__ bif, const float* __restrict__ bhf,
    const float* __restrict__ bib, const float* __restrict__ bhb,
    float* __restrict__ GX) {
  __shared__ __align__(16) float xs[32][36];    // [kk][s_local]
  __shared__ __align__(16) float wl[32][260];   // [kk][r_local]
  const int tid = threadIdx.x;
  const int s0 = blockIdx.x * 32, r0 = blockIdx.y * 256, dir = blockIdx.z;
  const float* W = dir ? wb : wf;
  const int tids = tid & 7;        // s-group (4 s each)
  const int tidr = tid >> 3;       // r-group (4 r each), 0..63
  float acc[4][4];
  #pragma unroll
  for (int a = 0; a < 4; ++a)
    #pragma unroll
    for (int b = 0; b < 4; ++b) acc[a][b] = 0.f;

  for (int kc = 0; kc < 10; ++kc) {
    const int k0 = kc * 32;
    __syncthreads();
    for (int e = tid; e < 1024; e += 512) {     // x tile (fused gather)
      int kk = e & 31, sl = e >> 5;
      int s = s0 + sl;
      int src = dir ? (SEQ - 1 - s) : s;
      int k = k0 + kk;
      float v;
      if (k < DE) v = emb[(size_t)sent[src] * DE + k];
      else        v = xemb[(size_t)extra[src] * DXX + (k - DE)];
      xs[kk][sl] = v;
    }
    for (int e = tid; e < 8192; e += 512) {     // w tile
      int kk = e & 31, rl = e >> 5;
      wl[kk][rl] = W[(size_t)(r0 + rl) * DIN + k0 + kk];
    }
    __syncthreads();
    #pragma unroll
    for (int kk = 0; kk < 32; ++kk) {
      float4 xv = *(const float4*)&xs[kk][4 * tids];
      float4 wv = *(const float4*)&wl[kk][4 * tidr];
      acc[0][0] += xv.x * wv.x; acc[0][1] += xv.x * wv.y; acc[0][2] += xv.x * wv.z; acc[0][3] += xv.x * wv.w;
      acc[1][0] += xv.y * wv.x; acc[1][1] += xv.y * wv.y; acc[1][2] += xv.y * wv.z; acc[1][3] += xv.y * wv.w;
      acc[2][0] += xv.z * wv.x; acc[2][1] += xv.z * wv.y; acc[2][2] += xv.z * wv.z; acc[2][3] += xv.z * wv.w;
      acc[3][0] += xv.w * wv.x; acc[3][1] += xv.w * wv.y; acc[3][2] += xv.w * wv.z; acc[3][3] += xv.w * wv.w;
    }
  }
  const float* BI = dir ? bib : bif;
  const float* BH = dir ? bhb : bhf;
  float4 b1 = *(const float4*)&BI[r0 + 4 * tidr];
  float4 b2 = *(const float4*)&BH[r0 + 4 * tidr];
  float bx = b1.x + b2.x, by = b1.y + b2.y, bz = b1.z + b2.z, bw = b1.w + b2.w;
  #pragma unroll
  for (int ss = 0; ss < 4; ++ss) {
    int s = s0 + 4 * tids + ss;
    float4 o;
    o.x = acc[ss][0] + bx; o.y = acc[ss][1] + by; o.z = acc[ss][2] + bz; o.w = acc[ss][3] + bw;
    *(float4*)&GX[((size_t)dir * SEQ + s) * G4 + r0 + 4 * tidr] = o;
  }
}

// ---------------------------------------------------------------------------
// K2: one LSTM timestep, both directions. grid 8 (= 2 dirs x 4 parts),
// block 256. Thread (gi,l) in part p computes gate row gi*256 + (64p+l):
// dot(W_hh[row], h_{t-1}) + gx[t][row]. Weights stream from L2 (hot slice
// per block). Lane gi==0 does the elementwise c/h update. No atomics, no
// spin; cross-step visibility via kernel dispatch boundaries.
// ---------------------------------------------------------------------------
__global__ __launch_bounds__(256) void k_step(
    const float* __restrict__ whf, const float* __restrict__ whb,
    const float* __restrict__ GX, float* __restrict__ H, float* __restrict__ C,
    int t) {
  const int dir = blockIdx.x >> 2;
  const int p   = blockIdx.x & 3;
  const int tid = threadIdx.x;
  const int gi = tid >> 6, l = tid & 63;
  const int j   = (p << 6) | l;          // element 0..255
  const int row = (gi << 8) | j;         // gate row 0..1023
  __shared__ __align__(16) float hl[HH];
  __shared__ float gl[4][64];
  hl[tid] = H[dir * HSTR + (size_t)t * HH + tid];   // h_{t-1}
  __syncthreads();
  const float4* w4 = (const float4*)((dir ? whb : whf) + (size_t)row * HH);
  const float4* h4 = (const float4*)hl;
  float a0 = 0.f, a1 = 0.f, a2 = 0.f, a3 = 0.f;
  #pragma unroll
  for (int i = 0; i < 64; ++i) {
    float4 wv = w4[i];
    float4 hv = h4[i];
    a0 += wv.x * hv.x; a1 += wv.y * hv.y; a2 += wv.z * hv.z; a3 += wv.w * hv.w;
  }
  float acc = GX[((size_t)dir * SEQ + t) * G4 + row] + ((a0 + a1) + (a2 + a3));
  gl[gi][l] = acc;
  __syncthreads();
  if (gi == 0) {
    float iv = gl[0][l], fv = gl[1][l], gv = gl[2][l], ov = gl[3][l];
    float ig = 1.f / (1.f + expf(-iv));
    float fg = 1.f / (1.f + expf(-fv));
    float gg = tanhf(gv);
    float og = 1.f / (1.f + expf(-ov));
    float c = fg * C[dir * HH + j] + ig * gg;
    float h = og * tanhf(c);
    C[dir * HH + j] = c;
    H[dir * HSTR + (size_t)(t + 1) * HH + j] = h;
  }
}

// ---------------------------------------------------------------------------
// K3: feats = [hf, hb_rev] @ fc_w.T + fc_b.  grid SEQ/16, block 256.
// HF/HB passed with +HH offset so index t maps to h_t.
// ---------------------------------------------------------------------------
__global__ __launch_bounds__(256) void k_feats(
    const float* __restrict__ HF, const float* __restrict__ HB,
    const float* __restrict__ fcw, const float* __restrict__ fcb,
    float* __restrict__ FE) {
  __shared__ float hlds[16][512];
  __shared__ float wl[64][65];
  const int tid = threadIdx.x;
  const int s0 = blockIdx.x * 16;
  for (int e = tid; e < 16 * 512; e += 256) {
    int sl = e >> 9, k = e & 511;
    float v = (k < HH) ? HF[(size_t)(s0 + sl) * HH + k]
                       : HB[(size_t)(SEQ - 1 - (s0 + sl)) * HH + (k - HH)];
    hlds[sl][k] = v;
  }
  const int j = tid & 63, sg = tid >> 6;
  float acc[4];
  #pragma unroll
  for (int q = 0; q < 4; ++q) acc[q] = fcb[j];
  for (int kc = 0; kc < 8; ++kc) {
    __syncthreads();
    for (int e = tid; e < 4096; e += 256) {
      int kk = e & 63, jj = e >> 6;
      wl[kk][jj] = fcw[(size_t)jj * 512 + kc * 64 + kk];
    }
    __syncthreads();
    #pragma unroll 8
    for (int kk = 0; kk < 64; ++kk) {
      float wv = wl[kk][j];
      int kg = kc * 64 + kk;
      #pragma unroll
      for (int q = 0; q < 4; ++q) acc[q] += hlds[4 * sg + q][kg] * wv;
    }
  }
  #pragma unroll
  for (int q = 0; q < 4; ++q)
    FE[(size_t)(s0 + 4 * sg + q) * NT + j] = acc[q];
}

// ---------------------------------------------------------------------------
// K4: Viterbi. 1 block x 256 threads (4 waves split the 64-way max).
// numpy-faithful: v = (score[i]+trans[i][j]) + feats[t][j], strict-> first-max.
// ---------------------------------------------------------------------------
__global__ __launch_bounds__(256) void k_viterbi(
    const float* __restrict__ feats, const float* __restrict__ start,
    const float* __restrict__ endv, const float* __restrict__ trans,
    unsigned char* __restrict__ bp, int* __restrict__ out) {
  __shared__ float tr[64 * 64];
  __shared__ float sc[64];
  __shared__ float pval[4][64];
  __shared__ int pidx[4][64];
  const int tid = threadIdx.x;
  for (int e = tid; e < 4096; e += 256) tr[e] = trans[e];
  if (tid < 64) sc[tid] = start[tid] + feats[tid];
  __syncthreads();
  const int w = tid >> 6, j = tid & 63;
  for (int t = 1; t < SEQ; ++t) {
    float fj = feats[t * NT + j];
    float best = -3.0e38f; int bi = 0;
    const int ibase = w << 4;
    #pragma unroll
    for (int ii = 0; ii < 16; ++ii) {
      int i = ibase + ii;
      float v = (sc[i] + tr[(i << 6) | j]) + fj;
      if (v > best) { best = v; bi = i; }
    }
    pval[w][j] = best; pidx[w][j] = bi;
    __syncthreads();
    if (w == 0) {
      float b = pval[0][j]; int x = pidx[0][j];
      if (pval[1][j] > b) { b = pval[1][j]; x = pidx[1][j]; }
      if (pval[2][j] > b) { b = pval[2][j]; x = pidx[2][j]; }
      if (pval[3][j] > b) { b = pval[3][j]; x = pidx[3][j]; }
      bp[t * NT + j] = (unsigned char)x;
      sc[j] = b;
    }
    __syncthreads();
  }
  if (tid == 0) {
    float best = -3.0e38f; int bt = 0;
    for (int i = 0; i < 64; ++i) {
      float v = sc[i] + endv[i];
      if (v > best) { best = v; bt = i; }
    }
    out[SEQ - 1] = bt;
    int tag = bt;
    for (int t = SEQ - 1; t >= 1; --t) {
      tag = bp[t * NT + tag];
      out[t - 1] = tag;
    }
  }
}

// ---------------------------------------------------------------------------
extern "C" void kernel_launch(void* const* d_in, const int* in_sizes, int n_in,
                              void* d_out, int out_size, void* d_ws, size_t ws_size,
                              hipStream_t stream) {
  // --- Defensive guards: any mismatch -> fail visibly (absmax), never fault.
  if (n_in < 19) return;
  if (in_sizes[0] != SEQ || in_sizes[1] != SEQ) return;              // sentence, extra
  if (in_sizes[2] != 1 || in_sizes[3] != 1) return;                  // b, e scalars
  if (in_sizes[4] != 100000 * DE) return;                            // emb
  if (in_sizes[5] != 1000 * DXX) return;                             // extra_emb
  if (in_sizes[6] != G4 * DIN || in_sizes[7] != G4 * HH) return;     // w_ih_f, w_hh_f
  if (in_sizes[8] != G4 || in_sizes[9] != G4) return;                // b_ih_f, b_hh_f
  if (in_sizes[10] != G4 * DIN || in_sizes[11] != G4 * HH) return;   // w_ih_b, w_hh_b
  if (in_sizes[14] != NT * 512 || in_sizes[15] != NT) return;        // fc_w, fc_b
  if (in_sizes[16] != NT || in_sizes[17] != NT) return;              // crf_start, crf_end
  if (in_sizes[18] != NT * NT) return;                               // crf_trans
  if (out_size < SEQ) return;
  if (ws_size < WS_NEEDED_BYTES) return;

  const int*   sent = (const int*)d_in[0];
  const int*   extra = (const int*)d_in[1];
  const float* emb  = (const float*)d_in[4];
  const float* xemb = (const float*)d_in[5];
  const float* wihf = (const float*)d_in[6];
  const float* whhf = (const float*)d_in[7];
  const float* bihf = (const float*)d_in[8];
  const float* bhhf = (const float*)d_in[9];
  const float* wihb = (const float*)d_in[10];
  const float* whhb = (const float*)d_in[11];
  const float* bihb = (const float*)d_in[12];
  const float* bhhb = (const float*)d_in[13];
  const float* fcw  = (const float*)d_in[14];
  const float* fcb  = (const float*)d_in[15];
  const float* cst  = (const float*)d_in[16];
  const float* cen  = (const float*)d_in[17];
  const float* ctr  = (const float*)d_in[18];

  float* ws = (float*)d_ws;
  float* GX = ws + OFF_GX;
  float* H  = ws + OFF_H;
  float* C  = ws + OFF_C;
  float* FE = ws + OFF_FE;
  unsigned char* BP = (unsigned char*)(ws + OFF_BP);

  k_init<<<1, 256, 0, stream>>>(H, C);
  k_gx<<<dim3(SEQ / 32, G4 / 256, 2), 512, 0, stream>>>(
      sent, extra, emb, xemb, wihf, wihb, bihf, bhhf, bihb, bhhb, GX);
  for (int t = 0; t < SEQ; ++t) {
    k_step<<<8, 256, 0, stream>>>(whhf, whhb, GX, H, C, t);
  }
  // HF[t] = h_f_t ; HB[trev] = h_b_trev (reversed time), both via +HH offset
  k_feats<<<SEQ / 16, 256, 0, stream>>>(H + HH, H + HSTR + HH, fcw, fcb, FE);
  k_viterbi<<<1, 256, 0, stream>>>(FE, cst, cen, ctr, BP, (int*)d_out);
}

// Round 5
// 13378.729 us; speedup vs baseline: 1.5524x; 1.5524x over previous
//
#include <hip/hip_runtime.h>
#include <hip/hip_cooperative_groups.h>
#include <stdint.h>

namespace cg = cooperative_groups;

// Problem constants
#define SEQ   2048
#define DE    256
#define DXX   64
#define DIN   320      // DE + DX
#define HH    256      // hidden per direction
#define G4    1024     // 4*HH
#define NT    64       // tags

// Workspace layout (float32 slot indices)
// GX [2][SEQ][G4] ; H [2][SEQ+1][HH] (slot 0 = h_{-1} = 0) ; C [2][HH] ;
// FE [SEQ][NT] ; BP u8 [SEQ][NT]
static constexpr size_t OFF_GX = 0;
static constexpr size_t OFF_H  = OFF_GX + (size_t)2 * SEQ * G4;        // 4194304
static constexpr size_t HSTR   = (size_t)(SEQ + 1) * HH;               // 524544
static constexpr size_t OFF_C  = OFF_H + 2 * HSTR;                     // 5243392
static constexpr size_t OFF_FE = OFF_C + 2 * HH;                       // 5243904
static constexpr size_t OFF_BP = OFF_FE + (size_t)SEQ * NT;            // 5374976
static constexpr size_t WS_NEEDED_BYTES = OFF_BP * 4 + (size_t)SEQ * NT; // ~21.6 MB

// ---------------------------------------------------------------------------
// K0: zero h_{-1} and c for both directions. 1 block x 256.
// ---------------------------------------------------------------------------
__global__ __launch_bounds__(256) void k_init(float* __restrict__ H,
                                              float* __restrict__ C) {
  const int tid = threadIdx.x;
  H[tid] = 0.f;              // h_{-1}, dir 0
  H[HSTR + tid] = 0.f;       // h_{-1}, dir 1
  C[tid] = 0.f;              // c, dir 0
  C[HH + tid] = 0.f;         // c, dir 1
}

// ---------------------------------------------------------------------------
// K1: fused gather + gx = x @ w_ih.T + (b_ih + b_hh), both directions.
// grid (SEQ/32, G4/256, 2), block 512.
// ---------------------------------------------------------------------------
__global__ __launch_bounds__(512) void k_gx(
    const int* __restrict__ sent, const int* __restrict__ extra,
    const float* __restrict__ emb, const float* __restrict__ xemb,
    const float* __restrict__ wf, const float* __restrict__ wb,
    const float* __restrict__ bif, const float* __restrict__ bhf,
    const float* __restrict__ bib, const float* __restrict__ bhb,
    float* __restrict__ GX) {
  __shared__ __align__(16) float xs[32][36];    // [kk][s_local]
  __shared__ __align__(16) float wl[32][260];   // [kk][r_local]
  const int tid = threadIdx.x;
  const int s0 = blockIdx.x * 32, r0 = blockIdx.y * 256, dir = blockIdx.z;
  const float* W = dir ? wb : wf;
  const int tids = tid & 7;        // s-group (4 s each)
  const int tidr = tid >> 3;       // r-group (4 r each), 0..63
  float acc[4][4];
  #pragma unroll
  for (int a = 0; a < 4; ++a)
    #pragma unroll
    for (int b = 0; b < 4; ++b) acc[a][b] = 0.f;

  for (int kc = 0; kc < 10; ++kc) {
    const int k0 = kc * 32;
    __syncthreads();
    for (int e = tid; e < 1024; e += 512) {     // x tile (fused gather)
      int kk = e & 31, sl = e >> 5;
      int s = s0 + sl;
      int src = dir ? (SEQ - 1 - s) : s;
      int k = k0 + kk;
      float v;
      if (k < DE) v = emb[(size_t)sent[src] * DE + k];
      else        v = xemb[(size_t)extra[src] * DXX + (k - DE)];
      xs[kk][sl] = v;
    }
    for (int e = tid; e < 8192; e += 512) {     // w tile
      int kk = e & 31, rl = e >> 5;
      wl[kk][rl] = W[(size_t)(r0 + rl) * DIN + k0 + kk];
    }
    __syncthreads();
    #pragma unroll
    for (int kk = 0; kk < 32; ++kk) {
      float4 xv = *(const float4*)&xs[kk][4 * tids];
      float4 wv = *(const float4*)&wl[kk][4 * tidr];
      acc[0][0] += xv.x * wv.x; acc[0][1] += xv.x * wv.y; acc[0][2] += xv.x * wv.z; acc[0][3] += xv.x * wv.w;
      acc[1][0] += xv.y * wv.x; acc[1][1] += xv.y * wv.y; acc[1][2] += xv.y * wv.z; acc[1][3] += xv.y * wv.w;
      acc[2][0] += xv.z * wv.x; acc[2][1] += xv.z * wv.y; acc[2][2] += xv.z * wv.z; acc[2][3] += xv.z * wv.w;
      acc[3][0] += xv.w * wv.x; acc[3][1] += xv.w * wv.y; acc[3][2] += xv.w * wv.z; acc[3][3] += xv.w * wv.w;
    }
  }
  const float* BI = dir ? bib : bif;
  const float* BH = dir ? bhb : bhf;
  float4 b1 = *(const float4*)&BI[r0 + 4 * tidr];
  float4 b2 = *(const float4*)&BH[r0 + 4 * tidr];
  float bx = b1.x + b2.x, by = b1.y + b2.y, bz = b1.z + b2.z, bw = b1.w + b2.w;
  #pragma unroll
  for (int ss = 0; ss < 4; ++ss) {
    int s = s0 + 4 * tids + ss;
    float4 o;
    o.x = acc[ss][0] + bx; o.y = acc[ss][1] + by; o.z = acc[ss][2] + bz; o.w = acc[ss][3] + bw;
    *(float4*)&GX[((size_t)dir * SEQ + s) * G4 + r0 + 4 * tidr] = o;
  }
}

// ---------------------------------------------------------------------------
// K2a: cooperative persistent BiLSTM. grid 8 (= 2 dirs x 4 parts), block 256.
// Each thread owns one w_hh row (256 fp32 in VGPRs, loaded once). One
// cg::grid().sync() per timestep. Numerics bit-identical to k_step.
// ---------------------------------------------------------------------------
__global__ __launch_bounds__(256, 1) void k_lstm_coop(
    const float* __restrict__ whf, const float* __restrict__ whb,
    const float* __restrict__ GX, float* __restrict__ H) {
  cg::grid_group grid = cg::this_grid();
  const int dir = blockIdx.x >> 2;
  const int p   = blockIdx.x & 3;
  const int tid = threadIdx.x;
  const int gi = tid >> 6, l = tid & 63;
  const int j   = (p << 6) | l;          // element 0..255
  const int row = (gi << 8) | j;         // gate row 0..1023
  const float4* w4g = (const float4*)((dir ? whb : whf) + (size_t)row * HH);
  float4 w[64];
  #pragma unroll
  for (int i = 0; i < 64; ++i) w[i] = w4g[i];
  const float* gxp = GX + (size_t)dir * SEQ * G4 + row;
  float* Hd = H + dir * HSTR;
  __shared__ __align__(16) float hl[HH];
  __shared__ float gl[4][64];
  float c = 0.f;

  for (int t = 0; t < SEQ; ++t) {
    hl[tid] = Hd[(size_t)t * HH + tid];   // h_{t-1}
    __syncthreads();
    const float4* h4 = (const float4*)hl;
    float a0 = 0.f, a1 = 0.f, a2 = 0.f, a3 = 0.f;
    #pragma unroll
    for (int i = 0; i < 64; ++i) {
      float4 wv = w[i];
      float4 hv = h4[i];
      a0 += wv.x * hv.x; a1 += wv.y * hv.y; a2 += wv.z * hv.z; a3 += wv.w * hv.w;
    }
    float acc = gxp[(size_t)t * G4] + ((a0 + a1) + (a2 + a3));
    gl[gi][l] = acc;
    __syncthreads();
    if (gi == 0) {
      float iv = gl[0][l], fv = gl[1][l], gv = gl[2][l], ov = gl[3][l];
      float ig = 1.f / (1.f + expf(-iv));
      float fg = 1.f / (1.f + expf(-fv));
      float gg = tanhf(gv);
      float og = 1.f / (1.f + expf(-ov));
      c = fg * c + ig * gg;
      float h = og * tanhf(c);
      Hd[(size_t)(t + 1) * HH + j] = h;
    }
    grid.sync();   // release h_t to all 8 blocks (device-scope barrier)
  }
}

// ---------------------------------------------------------------------------
// K2b: fallback — one LSTM timestep (R4 known-good path), grid 8, block 256.
// ---------------------------------------------------------------------------
__global__ __launch_bounds__(256) void k_step(
    const float* __restrict__ whf, const float* __restrict__ whb,
    const float* __restrict__ GX, float* __restrict__ H, float* __restrict__ C,
    int t) {
  const int dir = blockIdx.x >> 2;
  const int p   = blockIdx.x & 3;
  const int tid = threadIdx.x;
  const int gi = tid >> 6, l = tid & 63;
  const int j   = (p << 6) | l;
  const int row = (gi << 8) | j;
  __shared__ __align__(16) float hl[HH];
  __shared__ float gl[4][64];
  hl[tid] = H[dir * HSTR + (size_t)t * HH + tid];
  __syncthreads();
  const float4* w4 = (const float4*)((dir ? whb : whf) + (size_t)row * HH);
  const float4* h4 = (const float4*)hl;
  float a0 = 0.f, a1 = 0.f, a2 = 0.f, a3 = 0.f;
  #pragma unroll
  for (int i = 0; i < 64; ++i) {
    float4 wv = w4[i];
    float4 hv = h4[i];
    a0 += wv.x * hv.x; a1 += wv.y * hv.y; a2 += wv.z * hv.z; a3 += wv.w * hv.w;
  }
  float acc = GX[((size_t)dir * SEQ + t) * G4 + row] + ((a0 + a1) + (a2 + a3));
  gl[gi][l] = acc;
  __syncthreads();
  if (gi == 0) {
    float iv = gl[0][l], fv = gl[1][l], gv = gl[2][l], ov = gl[3][l];
    float ig = 1.f / (1.f + expf(-iv));
    float fg = 1.f / (1.f + expf(-fv));
    float gg = tanhf(gv);
    float og = 1.f / (1.f + expf(-ov));
    float c = fg * C[dir * HH + j] + ig * gg;
    float h = og * tanhf(c);
    C[dir * HH + j] = c;
    H[dir * HSTR + (size_t)(t + 1) * HH + j] = h;
  }
}

// ---------------------------------------------------------------------------
// K3: feats = [hf, hb_rev] @ fc_w.T + fc_b.  grid SEQ/16, block 256.
// ---------------------------------------------------------------------------
__global__ __launch_bounds__(256) void k_feats(
    const float* __restrict__ HF, const float* __restrict__ HB,
    const float* __restrict__ fcw, const float* __restrict__ fcb,
    float* __restrict__ FE) {
  __shared__ float hlds[16][512];
  __shared__ float wl[64][65];
  const int tid = threadIdx.x;
  const int s0 = blockIdx.x * 16;
  for (int e = tid; e < 16 * 512; e += 256) {
    int sl = e >> 9, k = e & 511;
    float v = (k < HH) ? HF[(size_t)(s0 + sl) * HH + k]
                       : HB[(size_t)(SEQ - 1 - (s0 + sl)) * HH + (k - HH)];
    hlds[sl][k] = v;
  }
  const int j = tid & 63, sg = tid >> 6;
  float acc[4];
  #pragma unroll
  for (int q = 0; q < 4; ++q) acc[q] = fcb[j];
  for (int kc = 0; kc < 8; ++kc) {
    __syncthreads();
    for (int e = tid; e < 4096; e += 256) {
      int kk = e & 63, jj = e >> 6;
      wl[kk][jj] = fcw[(size_t)jj * 512 + kc * 64 + kk];
    }
    __syncthreads();
    #pragma unroll 8
    for (int kk = 0; kk < 64; ++kk) {
      float wv = wl[kk][j];
      int kg = kc * 64 + kk;
      #pragma unroll
      for (int q = 0; q < 4; ++q) acc[q] += hlds[4 * sg + q][kg] * wv;
    }
  }
  #pragma unroll
  for (int q = 0; q < 4; ++q)
    FE[(size_t)(s0 + 4 * sg + q) * NT + j] = acc[q];
}

// ---------------------------------------------------------------------------
// K4: Viterbi. 1 block x 256 threads (4 waves split the 64-way max).
// numpy-faithful: v = (score[i]+trans[i][j]) + feats[t][j], strict-> first-max.
// ---------------------------------------------------------------------------
__global__ __launch_bounds__(256) void k_viterbi(
    const float* __restrict__ feats, const float* __restrict__ start,
    const float* __restrict__ endv, const float* __restrict__ trans,
    unsigned char* __restrict__ bp, int* __restrict__ out) {
  __shared__ float tr[64 * 64];
  __shared__ float sc[64];
  __shared__ float pval[4][64];
  __shared__ int pidx[4][64];
  const int tid = threadIdx.x;
  for (int e = tid; e < 4096; e += 256) tr[e] = trans[e];
  if (tid < 64) sc[tid] = start[tid] + feats[tid];
  __syncthreads();
  const int w = tid >> 6, j = tid & 63;
  for (int t = 1; t < SEQ; ++t) {
    float fj = feats[t * NT + j];
    float best = -3.0e38f; int bi = 0;
    const int ibase = w << 4;
    #pragma unroll
    for (int ii = 0; ii < 16; ++ii) {
      int i = ibase + ii;
      float v = (sc[i] + tr[(i << 6) | j]) + fj;
      if (v > best) { best = v; bi = i; }
    }
    pval[w][j] = best; pidx[w][j] = bi;
    __syncthreads();
    if (w == 0) {
      float b = pval[0][j]; int x = pidx[0][j];
      if (pval[1][j] > b) { b = pval[1][j]; x = pidx[1][j]; }
      if (pval[2][j] > b) { b = pval[2][j]; x = pidx[2][j]; }
      if (pval[3][j] > b) { b = pval[3][j]; x = pidx[3][j]; }
      bp[t * NT + j] = (unsigned char)x;
      sc[j] = b;
    }
    __syncthreads();
  }
  if (tid == 0) {
    float best = -3.0e38f; int bt = 0;
    for (int i = 0; i < 64; ++i) {
      float v = sc[i] + endv[i];
      if (v > best) { best = v; bt = i; }
    }
    out[SEQ - 1] = bt;
    int tag = bt;
    for (int t = SEQ - 1; t >= 1; --t) {
      tag = bp[t * NT + tag];
      out[t - 1] = tag;
    }
  }
}

// ---------------------------------------------------------------------------
extern "C" void kernel_launch(void* const* d_in, const int* in_sizes, int n_in,
                              void* d_out, int out_size, void* d_ws, size_t ws_size,
                              hipStream_t stream) {
  // --- Defensive guards: any mismatch -> fail visibly (absmax), never fault.
  if (n_in < 19) return;
  if (in_sizes[0] != SEQ || in_sizes[1] != SEQ) return;              // sentence, extra
  if (in_sizes[2] != 1 || in_sizes[3] != 1) return;                  // b, e scalars
  if (in_sizes[4] != 100000 * DE) return;                            // emb
  if (in_sizes[5] != 1000 * DXX) return;                             // extra_emb
  if (in_sizes[6] != G4 * DIN || in_sizes[7] != G4 * HH) return;     // w_ih_f, w_hh_f
  if (in_sizes[8] != G4 || in_sizes[9] != G4) return;                // b_ih_f, b_hh_f
  if (in_sizes[10] != G4 * DIN || in_sizes[11] != G4 * HH) return;   // w_ih_b, w_hh_b
  if (in_sizes[14] != NT * 512 || in_sizes[15] != NT) return;        // fc_w, fc_b
  if (in_sizes[16] != NT || in_sizes[17] != NT) return;              // crf_start, crf_end
  if (in_sizes[18] != NT * NT) return;                               // crf_trans
  if (out_size < SEQ) return;
  if (ws_size < WS_NEEDED_BYTES) return;

  const int*   sent = (const int*)d_in[0];
  const int*   extra = (const int*)d_in[1];
  const float* emb  = (const float*)d_in[4];
  const float* xemb = (const float*)d_in[5];
  const float* wihf = (const float*)d_in[6];
  const float* whhf = (const float*)d_in[7];
  const float* bihf = (const float*)d_in[8];
  const float* bhhf = (const float*)d_in[9];
  const float* wihb = (const float*)d_in[10];
  const float* whhb = (const float*)d_in[11];
  const float* bihb = (const float*)d_in[12];
  const float* bhhb = (const float*)d_in[13];
  const float* fcw  = (const float*)d_in[14];
  const float* fcb  = (const float*)d_in[15];
  const float* cst  = (const float*)d_in[16];
  const float* cen  = (const float*)d_in[17];
  const float* ctr  = (const float*)d_in[18];

  float* ws = (float*)d_ws;
  float* GX = ws + OFF_GX;
  float* H  = ws + OFF_H;
  float* C  = ws + OFF_C;
  float* FE = ws + OFF_FE;
  unsigned char* BP = (unsigned char*)(ws + OFF_BP);

  k_init<<<1, 256, 0, stream>>>(H, C);
  k_gx<<<dim3(SEQ / 32, G4 / 256, 2), 512, 0, stream>>>(
      sent, extra, emb, xemb, wihf, wihb, bihf, bhhf, bihb, bhhb, GX);

  // Cooperative persistent recurrence; on any launch error fall back to the
  // R4 per-step path (known-good, ~21 ms) so we never lose the round.
  {
    const float* a0 = whhf; const float* a1 = whhb;
    const float* a2 = GX;   float* a3 = H;
    void* args[] = { (void*)&a0, (void*)&a1, (void*)&a2, (void*)&a3 };
    hipError_t e = hipLaunchCooperativeKernel((const void*)k_lstm_coop,
                                              dim3(8), dim3(256), args, 0, stream);
    if (e != hipSuccess) {
      (void)hipGetLastError();   // clear sticky error
      for (int t = 0; t < SEQ; ++t)
        k_step<<<8, 256, 0, stream>>>(whhf, whhb, GX, H, C, t);
    }
  }

  // HF[t] = h_f_t ; HB[trev] = h_b_trev (reversed time), both via +HH offset
  k_feats<<<SEQ / 16, 256, 0, stream>>>(H + HH, H + HSTR + HH, fcw, fcb, FE);
  k_viterbi<<<1, 256, 0, stream>>>(FE, cst, cen, ctr, BP, (int*)d_out);
}

// Round 6
// 11159.789 us; speedup vs baseline: 1.8611x; 1.1988x over previous
//
#include <hip/hip_runtime.h>
#include <stdint.h>

// Problem constants
#define SEQ   2048
#define DE    256
#define DXX   64
#define DIN   320      // DE + DX
#define HH    256      // hidden per direction
#define G4    1024     // 4*HH
#define NT    64       // tags

// Workspace layout (float32 slot indices)
// GX [2][SEQ][G4] ; H [2][SEQ+1][HH] (slot 0 = h_{-1} = 0) ; C [2][HH] ;
// CNT u32[128] ; FE [SEQ][NT] ; BP u8 [SEQ][NT]
static constexpr size_t OFF_GX  = 0;
static constexpr size_t OFF_H   = OFF_GX + (size_t)2 * SEQ * G4;       // 4194304
static constexpr size_t HSTR    = (size_t)(SEQ + 1) * HH;              // 524544
static constexpr size_t OFF_C   = OFF_H + 2 * HSTR;                    // 5243392
static constexpr size_t OFF_CNT = OFF_C + 2 * HH;                      // 5243904
static constexpr size_t OFF_FE  = OFF_CNT + 128;                       // 5244032
static constexpr size_t OFF_BP  = OFF_FE + (size_t)SEQ * NT;           // 5375104
static constexpr size_t WS_NEEDED_BYTES = OFF_BP * 4 + (size_t)SEQ * NT; // ~21.6 MB

// ---------------------------------------------------------------------------
// K0: zero h_{-1}, c, and barrier counters. 1 block x 256. (No memset in
// capture — this kernel is the only initializer.)
// ---------------------------------------------------------------------------
__global__ __launch_bounds__(256) void k_init(float* __restrict__ H,
                                              float* __restrict__ C,
                                              unsigned* __restrict__ cnt) {
  const int tid = threadIdx.x;
  H[tid] = 0.f;              // h_{-1}, dir 0
  H[HSTR + tid] = 0.f;       // h_{-1}, dir 1
  C[tid] = 0.f;              // c, dir 0 (unused by sync kernel; kept zeroed)
  C[HH + tid] = 0.f;         // c, dir 1
  if (tid < 128) cnt[tid] = 0u;
}

// ---------------------------------------------------------------------------
// K1: fused gather + gx = x @ w_ih.T + (b_ih + b_hh), both directions.
// grid (SEQ/32, G4/256, 2), block 512.
// ---------------------------------------------------------------------------
__global__ __launch_bounds__(512) void k_gx(
    const int* __restrict__ sent, const int* __restrict__ extra,
    const float* __restrict__ emb, const float* __restrict__ xemb,
    const float* __restrict__ wf, const float* __restrict__ wb,
    const float* __restrict__ bif, const float* __restrict__ bhf,
    const float* __restrict__ bib, const float* __restrict__ bhb,
    float* __restrict__ GX) {
  __shared__ __align__(16) float xs[32][36];    // [kk][s_local]
  __shared__ __align__(16) float wl[32][260];   // [kk][r_local]
  const int tid = threadIdx.x;
  const int s0 = blockIdx.x * 32, r0 = blockIdx.y * 256, dir = blockIdx.z;
  const float* W = dir ? wb : wf;
  const int tids = tid & 7;        // s-group (4 s each)
  const int tidr = tid >> 3;       // r-group (4 r each), 0..63
  float acc[4][4];
  #pragma unroll
  for (int a = 0; a < 4; ++a)
    #pragma unroll
    for (int b = 0; b < 4; ++b) acc[a][b] = 0.f;

  for (int kc = 0; kc < 10; ++kc) {
    const int k0 = kc * 32;
    __syncthreads();
    for (int e = tid; e < 1024; e += 512) {     // x tile (fused gather)
      int kk = e & 31, sl = e >> 5;
      int s = s0 + sl;
      int src = dir ? (SEQ - 1 - s) : s;
      int k = k0 + kk;
      float v;
      if (k < DE) v = emb[(size_t)sent[src] * DE + k];
      else        v = xemb[(size_t)extra[src] * DXX + (k - DE)];
      xs[kk][sl] = v;
    }
    for (int e = tid; e < 8192; e += 512) {     // w tile
      int kk = e & 31, rl = e >> 5;
      wl[kk][rl] = W[(size_t)(r0 + rl) * DIN + k0 + kk];
    }
    __syncthreads();
    #pragma unroll
    for (int kk = 0; kk < 32; ++kk) {
      float4 xv = *(const float4*)&xs[kk][4 * tids];
      float4 wv = *(const float4*)&wl[kk][4 * tidr];
      acc[0][0] += xv.x * wv.x; acc[0][1] += xv.x * wv.y; acc[0][2] += xv.x * wv.z; acc[0][3] += xv.x * wv.w;
      acc[1][0] += xv.y * wv.x; acc[1][1] += xv.y * wv.y; acc[1][2] += xv.y * wv.z; acc[1][3] += xv.y * wv.w;
      acc[2][0] += xv.z * wv.x; acc[2][1] += xv.z * wv.y; acc[2][2] += xv.z * wv.z; acc[2][3] += xv.z * wv.w;
      acc[3][0] += xv.w * wv.x; acc[3][1] += xv.w * wv.y; acc[3][2] += xv.w * wv.z; acc[3][3] += xv.w * wv.w;
    }
  }
  const float* BI = dir ? bib : bif;
  const float* BH = dir ? bhb : bhf;
  float4 b1 = *(const float4*)&BI[r0 + 4 * tidr];
  float4 b2 = *(const float4*)&BH[r0 + 4 * tidr];
  float bx = b1.x + b2.x, by = b1.y + b2.y, bz = b1.z + b2.z, bw = b1.w + b2.w;
  #pragma unroll
  for (int ss = 0; ss < 4; ++ss) {
    int s = s0 + 4 * tids + ss;
    float4 o;
    o.x = acc[ss][0] + bx; o.y = acc[ss][1] + by; o.z = acc[ss][2] + bz; o.w = acc[ss][3] + bw;
    *(float4*)&GX[((size_t)dir * SEQ + s) * G4 + r0 + 4 * tidr] = o;
  }
}

// ---------------------------------------------------------------------------
// K2: persistent BiLSTM, hand-rolled per-direction barrier.
// grid 8 (= 2 dirs x 4 parts), block 256, 1 wave/SIMD (launch_bounds(256,1)
// allows up to 512 VGPRs so w[64] float4 can live in registers).
// Protocol per step: wave0 stores its 64 h values (relaxed, agent scope);
// lane 0's RELEASE fetch_add drains the wave's stores (per-wave vmcnt) and
// publishes; thread 0 of every block ACQUIRE-spins to target 4*t, then
// __syncthreads() and all threads reload h. Spin budget bounds any deadlock.
// Numerics bit-identical to R4/R5 (same accumulation order & gate math).
// ---------------------------------------------------------------------------
__global__ __launch_bounds__(256, 1) void k_lstm_sync(
    const float* __restrict__ whf, const float* __restrict__ whb,
    const float* __restrict__ GX, float* __restrict__ H,
    unsigned* __restrict__ cnt) {
  const int dir = blockIdx.x >> 2;
  const int p   = blockIdx.x & 3;
  const int tid = threadIdx.x;
  const int gi = tid >> 6, l = tid & 63;
  const int j   = (p << 6) | l;          // element 0..255
  const int row = (gi << 8) | j;         // gate row 0..1023
  const float4* w4g = (const float4*)((dir ? whb : whf) + (size_t)row * HH);
  float4 w[64];
  #pragma unroll
  for (int i = 0; i < 64; ++i) w[i] = w4g[i];
  const float* gxp = GX + (size_t)dir * SEQ * G4 + row;
  float* Hd = H + dir * HSTR;
  unsigned* cn = cnt + dir * 64;   // 256 B apart per direction

  __shared__ __align__(16) float hl[HH];
  __shared__ float gl[4][64];
  __shared__ int okflag;
  float c = 0.f;
  int budget = 2000000;   // bounded spin: worst ~150 ms then visible failure

  for (int t = 0; t < SEQ; ++t) {
    float gxv = gxp[(size_t)t * G4];   // h-independent: issues before the wait
    if (t > 0) {
      if (tid == 0) {
        const unsigned tgt = 4u * (unsigned)t;
        unsigned cv;
        while ((cv = __hip_atomic_load(cn, __ATOMIC_ACQUIRE,
                                       __HIP_MEMORY_SCOPE_AGENT)) < tgt &&
               budget > 0) {
          --budget;
          __builtin_amdgcn_s_sleep(1);
        }
        okflag = (cv >= tgt) ? 1 : 0;
      }
      __syncthreads();
      if (!okflag) break;   // block-uniform bail-out (deadlock failsafe)
    }
    hl[tid] = __hip_atomic_load(&Hd[(size_t)t * HH + tid], __ATOMIC_RELAXED,
                                __HIP_MEMORY_SCOPE_AGENT);
    __syncthreads();
    const float4* h4 = (const float4*)hl;
    float a0 = 0.f, a1 = 0.f, a2 = 0.f, a3 = 0.f;
    #pragma unroll
    for (int i = 0; i < 64; ++i) {
      float4 wv = w[i];
      float4 hv = h4[i];
      a0 += wv.x * hv.x; a1 += wv.y * hv.y; a2 += wv.z * hv.z; a3 += wv.w * hv.w;
    }
    float acc = gxv + ((a0 + a1) + (a2 + a3));
    gl[gi][l] = acc;
    __syncthreads();
    if (gi == 0) {   // wave 0 only: gates, state update, publish
      float iv = gl[0][l], fv = gl[1][l], gv = gl[2][l], ov = gl[3][l];
      float ig = 1.f / (1.f + expf(-iv));
      float fg = 1.f / (1.f + expf(-fv));
      float gg = tanhf(gv);
      float og = 1.f / (1.f + expf(-ov));
      c = fg * c + ig * gg;
      float h = og * tanhf(c);
      __hip_atomic_store(&Hd[(size_t)(t + 1) * HH + j], h, __ATOMIC_RELAXED,
                         __HIP_MEMORY_SCOPE_AGENT);
      if (l == 0) {
        // RELEASE drains this wave's vmcnt (all 64 h-stores) before publish.
        __hip_atomic_fetch_add(cn, 1u, __ATOMIC_RELEASE,
                               __HIP_MEMORY_SCOPE_AGENT);
      }
    }
  }
}

// ---------------------------------------------------------------------------
// K3: feats = [hf, hb_rev] @ fc_w.T + fc_b.  grid SEQ/16, block 256.
// ---------------------------------------------------------------------------
__global__ __launch_bounds__(256) void k_feats(
    const float* __restrict__ HF, const float* __restrict__ HB,
    const float* __restrict__ fcw, const float* __restrict__ fcb,
    float* __restrict__ FE) {
  __shared__ float hlds[16][512];
  __shared__ float wl[64][65];
  const int tid = threadIdx.x;
  const int s0 = blockIdx.x * 16;
  for (int e = tid; e < 16 * 512; e += 256) {
    int sl = e >> 9, k = e & 511;
    float v = (k < HH) ? HF[(size_t)(s0 + sl) * HH + k]
                       : HB[(size_t)(SEQ - 1 - (s0 + sl)) * HH + (k - HH)];
    hlds[sl][k] = v;
  }
  const int j = tid & 63, sg = tid >> 6;
  float acc[4];
  #pragma unroll
  for (int q = 0; q < 4; ++q) acc[q] = fcb[j];
  for (int kc = 0; kc < 8; ++kc) {
    __syncthreads();
    for (int e = tid; e < 4096; e += 256) {
      int kk = e & 63, jj = e >> 6;
      wl[kk][jj] = fcw[(size_t)jj * 512 + kc * 64 + kk];
    }
    __syncthreads();
    #pragma unroll 8
    for (int kk = 0; kk < 64; ++kk) {
      float wv = wl[kk][j];
      int kg = kc * 64 + kk;
      #pragma unroll
      for (int q = 0; q < 4; ++q) acc[q] += hlds[4 * sg + q][kg] * wv;
    }
  }
  #pragma unroll
  for (int q = 0; q < 4; ++q)
    FE[(size_t)(s0 + 4 * sg + q) * NT + j] = acc[q];
}

// ---------------------------------------------------------------------------
// K4: Viterbi. 1 block x 256 threads (4 waves split the 64-way max).
// numpy-faithful: v = (score[i]+trans[i][j]) + feats[t][j], strict-> first-max.
// ---------------------------------------------------------------------------
__global__ __launch_bounds__(256) void k_viterbi(
    const float* __restrict__ feats, const float* __restrict__ start,
    const float* __restrict__ endv, const float* __restrict__ trans,
    unsigned char* __restrict__ bp, int* __restrict__ out) {
  __shared__ float tr[64 * 64];
  __shared__ float sc[64];
  __shared__ float pval[4][64];
  __shared__ int pidx[4][64];
  const int tid = threadIdx.x;
  for (int e = tid; e < 4096; e += 256) tr[e] = trans[e];
  if (tid < 64) sc[tid] = start[tid] + feats[tid];
  __syncthreads();
  const int w = tid >> 6, j = tid & 63;
  for (int t = 1; t < SEQ; ++t) {
    float fj = feats[t * NT + j];
    float best = -3.0e38f; int bi = 0;
    const int ibase = w << 4;
    #pragma unroll
    for (int ii = 0; ii < 16; ++ii) {
      int i = ibase + ii;
      float v = (sc[i] + tr[(i << 6) | j]) + fj;
      if (v > best) { best = v; bi = i; }
    }
    pval[w][j] = best; pidx[w][j] = bi;
    __syncthreads();
    if (w == 0) {
      float b = pval[0][j]; int x = pidx[0][j];
      if (pval[1][j] > b) { b = pval[1][j]; x = pidx[1][j]; }
      if (pval[2][j] > b) { b = pval[2][j]; x = pidx[2][j]; }
      if (pval[3][j] > b) { b = pval[3][j]; x = pidx[3][j]; }
      bp[t * NT + j] = (unsigned char)x;
      sc[j] = b;
    }
    __syncthreads();
  }
  if (tid == 0) {
    float best = -3.0e38f; int bt = 0;
    for (int i = 0; i < 64; ++i) {
      float v = sc[i] + endv[i];
      if (v > best) { best = v; bt = i; }
    }
    out[SEQ - 1] = bt;
    int tag = bt;
    for (int t = SEQ - 1; t >= 1; --t) {
      tag = bp[t * NT + tag];
      out[t - 1] = tag;
    }
  }
}

// ---------------------------------------------------------------------------
extern "C" void kernel_launch(void* const* d_in, const int* in_sizes, int n_in,
                              void* d_out, int out_size, void* d_ws, size_t ws_size,
                              hipStream_t stream) {
  // --- Defensive guards: any mismatch -> fail visibly (absmax), never fault.
  if (n_in < 19) return;
  if (in_sizes[0] != SEQ || in_sizes[1] != SEQ) return;              // sentence, extra
  if (in_sizes[2] != 1 || in_sizes[3] != 1) return;                  // b, e scalars
  if (in_sizes[4] != 100000 * DE) return;                            // emb
  if (in_sizes[5] != 1000 * DXX) return;                             // extra_emb
  if (in_sizes[6] != G4 * DIN || in_sizes[7] != G4 * HH) return;     // w_ih_f, w_hh_f
  if (in_sizes[8] != G4 || in_sizes[9] != G4) return;                // b_ih_f, b_hh_f
  if (in_sizes[10] != G4 * DIN || in_sizes[11] != G4 * HH) return;   // w_ih_b, w_hh_b
  if (in_sizes[14] != NT * 512 || in_sizes[15] != NT) return;        // fc_w, fc_b
  if (in_sizes[16] != NT || in_sizes[17] != NT) return;              // crf_start, crf_end
  if (in_sizes[18] != NT * NT) return;                               // crf_trans
  if (out_size < SEQ) return;
  if (ws_size < WS_NEEDED_BYTES) return;

  const int*   sent = (const int*)d_in[0];
  const int*   extra = (const int*)d_in[1];
  const float* emb  = (const float*)d_in[4];
  const float* xemb = (const float*)d_in[5];
  const float* wihf = (const float*)d_in[6];
  const float* whhf = (const float*)d_in[7];
  const float* bihf = (const float*)d_in[8];
  const float* bhhf = (const float*)d_in[9];
  const float* wihb = (const float*)d_in[10];
  const float* whhb = (const float*)d_in[11];
  const float* bihb = (const float*)d_in[12];
  const float* bhhb = (const float*)d_in[13];
  const float* fcw  = (const float*)d_in[14];
  const float* fcb  = (const float*)d_in[15];
  const float* cst  = (const float*)d_in[16];
  const float* cen  = (const float*)d_in[17];
  const float* ctr  = (const float*)d_in[18];

  float* ws = (float*)d_ws;
  float* GX = ws + OFF_GX;
  float* H  = ws + OFF_H;
  float* C  = ws + OFF_C;
  unsigned* CNT = (unsigned*)(ws + OFF_CNT);
  float* FE = ws + OFF_FE;
  unsigned char* BP = (unsigned char*)(ws + OFF_BP);

  k_init<<<1, 256, 0, stream>>>(H, C, CNT);
  k_gx<<<dim3(SEQ / 32, G4 / 256, 2), 512, 0, stream>>>(
      sent, extra, emb, xemb, wihf, wihb, bihf, bhhf, bihb, bhhb, GX);
  k_lstm_sync<<<8, 256, 0, stream>>>(whhf, whhb, GX, H, CNT);
  // HF[t] = h_f_t ; HB[trev] = h_b_trev (reversed time), both via +HH offset
  k_feats<<<SEQ / 16, 256, 0, stream>>>(H + HH, H + HSTR + HH, fcw, fcb, FE);
  k_viterbi<<<1, 256, 0, stream>>>(FE, cst, cen, ctr, BP, (int*)d_out);
}

// Round 7
// 6057.032 us; speedup vs baseline: 3.4290x; 1.8425x over previous
//
#include <hip/hip_runtime.h>
#include <stdint.h>

// Problem constants
#define SEQ   2048
#define DE    256
#define DXX   64
#define DIN   320      // DE + DX
#define HH    256      // hidden per direction
#define G4    1024     // 4*HH
#define NT    64       // tags

// Workspace layout (float32 slot indices)
// GX [2][SEQ][G4] ; H [2][SEQ][HH] ; SLOT u64[2][256] (tagged h exchange) ;
// FE [SEQ][NT] ; BP u8 [SEQ][NT]
static constexpr size_t OFF_GX = 0;
static constexpr size_t OFF_H  = OFF_GX + (size_t)2 * SEQ * G4;        // 4194304
static constexpr size_t HSTR   = (size_t)SEQ * HH;                     // 524288
static constexpr size_t OFF_SL = OFF_H + 2 * HSTR;                     // 5242880 (8B-aligned)
static constexpr size_t OFF_FE = OFF_SL + 1024;                        // 5243904
static constexpr size_t OFF_BP = OFF_FE + (size_t)SEQ * NT;            // 5374976
static constexpr size_t WS_NEEDED_BYTES = OFF_BP * 4 + (size_t)SEQ * NT; // ~21.6 MB

// ---------------------------------------------------------------------------
// K0: reset tagged slots to (h=0, tag=0) == h_{-1}. 1 block x 256.
// ---------------------------------------------------------------------------
__global__ __launch_bounds__(256) void k_init(unsigned long long* __restrict__ slot) {
  const int tid = threadIdx.x;
  slot[tid] = 0ull;          // dir 0
  slot[256 + tid] = 0ull;    // dir 1
}

// ---------------------------------------------------------------------------
// K1: fused gather + gx = x @ w_ih.T + (b_ih + b_hh), both directions.
// grid (SEQ/32, G4/256, 2), block 512.
// ---------------------------------------------------------------------------
__global__ __launch_bounds__(512) void k_gx(
    const int* __restrict__ sent, const int* __restrict__ extra,
    const float* __restrict__ emb, const float* __restrict__ xemb,
    const float* __restrict__ wf, const float* __restrict__ wb,
    const float* __restrict__ bif, const float* __restrict__ bhf,
    const float* __restrict__ bib, const float* __restrict__ bhb,
    float* __restrict__ GX) {
  __shared__ __align__(16) float xs[32][36];    // [kk][s_local]
  __shared__ __align__(16) float wl[32][260];   // [kk][r_local]
  const int tid = threadIdx.x;
  const int s0 = blockIdx.x * 32, r0 = blockIdx.y * 256, dir = blockIdx.z;
  const float* W = dir ? wb : wf;
  const int tids = tid & 7;        // s-group (4 s each)
  const int tidr = tid >> 3;       // r-group (4 r each), 0..63
  float acc[4][4];
  #pragma unroll
  for (int a = 0; a < 4; ++a)
    #pragma unroll
    for (int b = 0; b < 4; ++b) acc[a][b] = 0.f;

  for (int kc = 0; kc < 10; ++kc) {
    const int k0 = kc * 32;
    __syncthreads();
    for (int e = tid; e < 1024; e += 512) {     // x tile (fused gather)
      int kk = e & 31, sl = e >> 5;
      int s = s0 + sl;
      int src = dir ? (SEQ - 1 - s) : s;
      int k = k0 + kk;
      float v;
      if (k < DE) v = emb[(size_t)sent[src] * DE + k];
      else        v = xemb[(size_t)extra[src] * DXX + (k - DE)];
      xs[kk][sl] = v;
    }
    for (int e = tid; e < 8192; e += 512) {     // w tile
      int kk = e & 31, rl = e >> 5;
      wl[kk][rl] = W[(size_t)(r0 + rl) * DIN + k0 + kk];
    }
    __syncthreads();
    #pragma unroll
    for (int kk = 0; kk < 32; ++kk) {
      float4 xv = *(const float4*)&xs[kk][4 * tids];
      float4 wv = *(const float4*)&wl[kk][4 * tidr];
      acc[0][0] += xv.x * wv.x; acc[0][1] += xv.x * wv.y; acc[0][2] += xv.x * wv.z; acc[0][3] += xv.x * wv.w;
      acc[1][0] += xv.y * wv.x; acc[1][1] += xv.y * wv.y; acc[1][2] += xv.y * wv.z; acc[1][3] += xv.y * wv.w;
      acc[2][0] += xv.z * wv.x; acc[2][1] += xv.z * wv.y; acc[2][2] += xv.z * wv.z; acc[2][3] += xv.z * wv.w;
      acc[3][0] += xv.w * wv.x; acc[3][1] += xv.w * wv.y; acc[3][2] += xv.w * wv.z; acc[3][3] += xv.w * wv.w;
    }
  }
  const float* BI = dir ? bib : bif;
  const float* BH = dir ? bhb : bhf;
  float4 b1 = *(const float4*)&BI[r0 + 4 * tidr];
  float4 b2 = *(const float4*)&BH[r0 + 4 * tidr];
  float bx = b1.x + b2.x, by = b1.y + b2.y, bz = b1.z + b2.z, bw = b1.w + b2.w;
  #pragma unroll
  for (int ss = 0; ss < 4; ++ss) {
    int s = s0 + 4 * tids + ss;
    float4 o;
    o.x = acc[ss][0] + bx; o.y = acc[ss][1] + by; o.z = acc[ss][2] + bz; o.w = acc[ss][3] + bw;
    *(float4*)&GX[((size_t)dir * SEQ + s) * G4 + r0 + 4 * tidr] = o;
  }
}

// ---------------------------------------------------------------------------
// K2: persistent BiLSTM with tagged-slot h exchange.
// grid 8 (= 2 dirs x 4 parts), block 512 (= 2 halves x 256 rows).
// Thread (half, r) owns a HALF gate row: 128 fp32 weights = 32 float4 = 128
// VGPRs (register-resident under launch_bounds(512,2): <=256 VGPR cap).
// Exchange: publisher packs (h, t+1) into one 8B relaxed agent atomic store;
// reader tid<256 polls ITS slot until tag==t — data rides inside the atom,
// so no counter / acquire fence / store drain on the critical path (1 LLC
// hop instead of R6's 4). Polls are budget-bounded; barriers unconditional.
// ---------------------------------------------------------------------------
__global__ __launch_bounds__(512, 2) void k_lstm_tag(
    const float* __restrict__ whf, const float* __restrict__ whb,
    const float* __restrict__ GX, float* __restrict__ H,
    unsigned long long* __restrict__ slot) {
  const int dir = blockIdx.x >> 2;
  const int p   = blockIdx.x & 3;
  const int tid = threadIdx.x;
  const int half = tid >> 8;           // 0/1: which 128-wide k-slice
  const int r    = tid & 255;          // local row 0..255
  const int gi = r >> 6, l = r & 63;
  const int j   = (p << 6) | l;        // h element this block owns (lane l)
  const int row = (gi << 8) | j;       // gate row 0..1023
  const float4* w4g =
      (const float4*)((dir ? whb : whf) + (size_t)row * HH) + half * 32;
  float4 w[32];
  #pragma unroll
  for (int i = 0; i < 32; ++i) w[i] = w4g[i];
  const float* gxp = GX + (size_t)dir * SEQ * G4 + row;   // used by half==0
  float* Hd = H + (size_t)dir * HSTR;
  unsigned long long* sl = slot + dir * 256;

  __shared__ __align__(16) float hl[HH];
  __shared__ float ps[2][256];
  __shared__ float gl[4][64];
  float c = 0.f;
  int budget = 1 << 18;   // bounded polling: worst ~80 ms then visible failure

  for (int t = 0; t < SEQ; ++t) {
    float gxv = 0.f;
    if (half == 0) gxv = gxp[(size_t)t * G4];  // HBM prefetch, hidden by poll
    if (tid < 256) {
      unsigned long long v;
      do {
        v = __hip_atomic_load(&sl[tid], __ATOMIC_RELAXED,
                              __HIP_MEMORY_SCOPE_AGENT);
      } while ((unsigned)(v >> 32) != (unsigned)t && --budget > 0);
      union { unsigned u; float f; } cv; cv.u = (unsigned)v;
      hl[tid] = cv.f;                  // h_{t-1}[tid]
    }
    __syncthreads();
    const float4* h4 = (const float4*)hl + half * 32;
    float a0 = 0.f, a1 = 0.f, a2 = 0.f, a3 = 0.f;
    #pragma unroll
    for (int i = 0; i < 32; ++i) {
      float4 wv = w[i];
      float4 hv = h4[i];
      a0 += wv.x * hv.x; a1 += wv.y * hv.y; a2 += wv.z * hv.z; a3 += wv.w * hv.w;
    }
    ps[half][r] = (a0 + a1) + (a2 + a3);
    __syncthreads();
    if (tid < 256) {
      float acc = gxv + (ps[0][tid] + ps[1][tid]);
      gl[tid >> 6][tid & 63] = acc;
    }
    __syncthreads();
    if (tid < 64) {   // lanes of wave 0: gates, state update, publish
      float iv = gl[0][tid], fv = gl[1][tid], gv = gl[2][tid], ov = gl[3][tid];
      float ig = 1.f / (1.f + expf(-iv));
      float fg = 1.f / (1.f + expf(-fv));
      float gg = tanhf(gv);
      float og = 1.f / (1.f + expf(-ov));
      c = fg * c + ig * gg;
      float h = og * tanhf(c);
      int jj = (p << 6) | tid;
      Hd[(size_t)t * HH + jj] = h;               // plain store for k_feats
      union { float f; unsigned u; } hu; hu.f = h;
      unsigned long long pk =
          ((unsigned long long)(unsigned)(t + 1) << 32) | hu.u;
      __hip_atomic_store(&sl[jj], pk, __ATOMIC_RELAXED,
                         __HIP_MEMORY_SCOPE_AGENT);
    }
  }
}

// ---------------------------------------------------------------------------
// K3: feats = [hf, hb_rev] @ fc_w.T + fc_b.  grid SEQ/16, block 256.
// ---------------------------------------------------------------------------
__global__ __launch_bounds__(256) void k_feats(
    const float* __restrict__ HF, const float* __restrict__ HB,
    const float* __restrict__ fcw, const float* __restrict__ fcb,
    float* __restrict__ FE) {
  __shared__ float hlds[16][512];
  __shared__ float wl[64][65];
  const int tid = threadIdx.x;
  const int s0 = blockIdx.x * 16;
  for (int e = tid; e < 16 * 512; e += 256) {
    int sl = e >> 9, k = e & 511;
    float v = (k < HH) ? HF[(size_t)(s0 + sl) * HH + k]
                       : HB[(size_t)(SEQ - 1 - (s0 + sl)) * HH + (k - HH)];
    hlds[sl][k] = v;
  }
  const int j = tid & 63, sg = tid >> 6;
  float acc[4];
  #pragma unroll
  for (int q = 0; q < 4; ++q) acc[q] = fcb[j];
  for (int kc = 0; kc < 8; ++kc) {
    __syncthreads();
    for (int e = tid; e < 4096; e += 256) {
      int kk = e & 63, jj = e >> 6;
      wl[kk][jj] = fcw[(size_t)jj * 512 + kc * 64 + kk];
    }
    __syncthreads();
    #pragma unroll 8
    for (int kk = 0; kk < 64; ++kk) {
      float wv = wl[kk][j];
      int kg = kc * 64 + kk;
      #pragma unroll
      for (int q = 0; q < 4; ++q) acc[q] += hlds[4 * sg + q][kg] * wv;
    }
  }
  #pragma unroll
  for (int q = 0; q < 4; ++q)
    FE[(size_t)(s0 + 4 * sg + q) * NT + j] = acc[q];
}

// ---------------------------------------------------------------------------
// K4: Viterbi. 1 block x 256 threads (4 waves split the 64-way max).
// numpy-faithful: v = (score[i]+trans[i][j]) + feats[t][j], strict-> first-max.
// ---------------------------------------------------------------------------
__global__ __launch_bounds__(256) void k_viterbi(
    const float* __restrict__ feats, const float* __restrict__ start,
    const float* __restrict__ endv, const float* __restrict__ trans,
    unsigned char* __restrict__ bp, int* __restrict__ out) {
  __shared__ float tr[64 * 64];
  __shared__ float sc[64];
  __shared__ float pval[4][64];
  __shared__ int pidx[4][64];
  const int tid = threadIdx.x;
  for (int e = tid; e < 4096; e += 256) tr[e] = trans[e];
  if (tid < 64) sc[tid] = start[tid] + feats[tid];
  __syncthreads();
  const int w = tid >> 6, j = tid & 63;
  for (int t = 1; t < SEQ; ++t) {
    float fj = feats[t * NT + j];
    float best = -3.0e38f; int bi = 0;
    const int ibase = w << 4;
    #pragma unroll
    for (int ii = 0; ii < 16; ++ii) {
      int i = ibase + ii;
      float v = (sc[i] + tr[(i << 6) | j]) + fj;
      if (v > best) { best = v; bi = i; }
    }
    pval[w][j] = best; pidx[w][j] = bi;
    __syncthreads();
    if (w == 0) {
      float b = pval[0][j]; int x = pidx[0][j];
      if (pval[1][j] > b) { b = pval[1][j]; x = pidx[1][j]; }
      if (pval[2][j] > b) { b = pval[2][j]; x = pidx[2][j]; }
      if (pval[3][j] > b) { b = pval[3][j]; x = pidx[3][j]; }
      bp[t * NT + j] = (unsigned char)x;
      sc[j] = b;
    }
    __syncthreads();
  }
  if (tid == 0) {
    float best = -3.0e38f; int bt = 0;
    for (int i = 0; i < 64; ++i) {
      float v = sc[i] + endv[i];
      if (v > best) { best = v; bt = i; }
    }
    out[SEQ - 1] = bt;
    int tag = bt;
    for (int t = SEQ - 1; t >= 1; --t) {
      tag = bp[t * NT + tag];
      out[t - 1] = tag;
    }
  }
}

// ---------------------------------------------------------------------------
extern "C" void kernel_launch(void* const* d_in, const int* in_sizes, int n_in,
                              void* d_out, int out_size, void* d_ws, size_t ws_size,
                              hipStream_t stream) {
  // --- Defensive guards: any mismatch -> fail visibly (absmax), never fault.
  if (n_in < 19) return;
  if (in_sizes[0] != SEQ || in_sizes[1] != SEQ) return;              // sentence, extra
  if (in_sizes[2] != 1 || in_sizes[3] != 1) return;                  // b, e scalars
  if (in_sizes[4] != 100000 * DE) return;                            // emb
  if (in_sizes[5] != 1000 * DXX) return;                             // extra_emb
  if (in_sizes[6] != G4 * DIN || in_sizes[7] != G4 * HH) return;     // w_ih_f, w_hh_f
  if (in_sizes[8] != G4 || in_sizes[9] != G4) return;                // b_ih_f, b_hh_f
  if (in_sizes[10] != G4 * DIN || in_sizes[11] != G4 * HH) return;   // w_ih_b, w_hh_b
  if (in_sizes[14] != NT * 512 || in_sizes[15] != NT) return;        // fc_w, fc_b
  if (in_sizes[16] != NT || in_sizes[17] != NT) return;              // crf_start, crf_end
  if (in_sizes[18] != NT * NT) return;                               // crf_trans
  if (out_size < SEQ) return;
  if (ws_size < WS_NEEDED_BYTES) return;

  const int*   sent = (const int*)d_in[0];
  const int*   extra = (const int*)d_in[1];
  const float* emb  = (const float*)d_in[4];
  const float* xemb = (const float*)d_in[5];
  const float* wihf = (const float*)d_in[6];
  const float* whhf = (const float*)d_in[7];
  const float* bihf = (const float*)d_in[8];
  const float* bhhf = (const float*)d_in[9];
  const float* wihb = (const float*)d_in[10];
  const float* whhb = (const float*)d_in[11];
  const float* bihb = (const float*)d_in[12];
  const float* bhhb = (const float*)d_in[13];
  const float* fcw  = (const float*)d_in[14];
  const float* fcb  = (const float*)d_in[15];
  const float* cst  = (const float*)d_in[16];
  const float* cen  = (const float*)d_in[17];
  const float* ctr  = (const float*)d_in[18];

  float* ws = (float*)d_ws;
  float* GX = ws + OFF_GX;
  float* H  = ws + OFF_H;
  unsigned long long* SLOT = (unsigned long long*)(ws + OFF_SL);
  float* FE = ws + OFF_FE;
  unsigned char* BP = (unsigned char*)(ws + OFF_BP);

  k_init<<<1, 256, 0, stream>>>(SLOT);
  k_gx<<<dim3(SEQ / 32, G4 / 256, 2), 512, 0, stream>>>(
      sent, extra, emb, xemb, wihf, wihb, bihf, bhhf, bihb, bhhb, GX);
  k_lstm_tag<<<8, 512, 0, stream>>>(whhf, whhb, GX, H, SLOT);
  k_feats<<<SEQ / 16, 256, 0, stream>>>(H, H + HSTR, fcw, fcb, FE);
  k_viterbi<<<1, 256, 0, stream>>>(FE, cst, cen, ctr, BP, (int*)d_out);
}

// Round 9
// 5510.787 us; speedup vs baseline: 3.7689x; 1.0991x over previous
//
#include <hip/hip_runtime.h>
#include <stdint.h>

// Problem constants
#define SEQ   2048
#define DE    256
#define DXX   64
#define DIN   320      // DE + DX
#define HH    256      // hidden per direction
#define G4    1024     // 4*HH
#define NT    64       // tags

// Workspace layout (float32 slot indices)
// GX [2][SEQ][G4] ; H [2][SEQ][HH] ; SLOT u64[2][2][256] (double-buffered
// tagged h exchange: [dir][buf][elem]) ; FE [SEQ][NT] ; BP u8 [SEQ][NT]
static constexpr size_t OFF_GX = 0;
static constexpr size_t OFF_H  = OFF_GX + (size_t)2 * SEQ * G4;        // 4194304
static constexpr size_t HSTR   = (size_t)SEQ * HH;                     // 524288
static constexpr size_t OFF_SL = OFF_H + 2 * HSTR;                     // 5242880 (8B-aligned)
static constexpr size_t OFF_FE = OFF_SL + 2048;                        // 5244928
static constexpr size_t OFF_BP = OFF_FE + (size_t)SEQ * NT;            // 5376000
static constexpr size_t WS_NEEDED_BYTES = OFF_BP * 4 + (size_t)SEQ * NT; // ~21.6 MB

// ---------------------------------------------------------------------------
// K0: reset both slot buffers to (h=0, tag=0). Buffer 0 == h_{-1} for t=0.
// ---------------------------------------------------------------------------
__global__ __launch_bounds__(256) void k_init(unsigned long long* __restrict__ slot) {
  const int tid = threadIdx.x;
  #pragma unroll
  for (int b = 0; b < 4; ++b) slot[b * 256 + tid] = 0ull;   // 2 dirs x 2 bufs
}

// ---------------------------------------------------------------------------
// K1: fused gather + gx = x @ w_ih.T + (b_ih + b_hh), both directions.
// grid (SEQ/32, G4/256, 2), block 512.
// ---------------------------------------------------------------------------
__global__ __launch_bounds__(512) void k_gx(
    const int* __restrict__ sent, const int* __restrict__ extra,
    const float* __restrict__ emb, const float* __restrict__ xemb,
    const float* __restrict__ wf, const float* __restrict__ wb,
    const float* __restrict__ bif, const float* __restrict__ bhf,
    const float* __restrict__ bib, const float* __restrict__ bhb,
    float* __restrict__ GX) {
  __shared__ __align__(16) float xs[32][36];    // [kk][s_local]
  __shared__ __align__(16) float wl[32][260];   // [kk][r_local]
  const int tid = threadIdx.x;
  const int s0 = blockIdx.x * 32, r0 = blockIdx.y * 256, dir = blockIdx.z;
  const float* W = dir ? wb : wf;
  const int tids = tid & 7;        // s-group (4 s each)
  const int tidr = tid >> 3;       // r-group (4 r each), 0..63
  float acc[4][4];
  #pragma unroll
  for (int a = 0; a < 4; ++a)
    #pragma unroll
    for (int b = 0; b < 4; ++b) acc[a][b] = 0.f;

  for (int kc = 0; kc < 10; ++kc) {
    const int k0 = kc * 32;
    __syncthreads();
    for (int e = tid; e < 1024; e += 512) {     // x tile (fused gather)
      int kk = e & 31, sl = e >> 5;
      int s = s0 + sl;
      int src = dir ? (SEQ - 1 - s) : s;
      int k = k0 + kk;
      float v;
      if (k < DE) v = emb[(size_t)sent[src] * DE + k];
      else        v = xemb[(size_t)extra[src] * DXX + (k - DE)];
      xs[kk][sl] = v;
    }
    for (int e = tid; e < 8192; e += 512) {     // w tile
      int kk = e & 31, rl = e >> 5;
      wl[kk][rl] = W[(size_t)(r0 + rl) * DIN + k0 + kk];
    }
    __syncthreads();
    #pragma unroll
    for (int kk = 0; kk < 32; ++kk) {
      float4 xv = *(const float4*)&xs[kk][4 * tids];
      float4 wv = *(const float4*)&wl[kk][4 * tidr];
      acc[0][0] += xv.x * wv.x; acc[0][1] += xv.x * wv.y; acc[0][2] += xv.x * wv.z; acc[0][3] += xv.x * wv.w;
      acc[1][0] += xv.y * wv.x; acc[1][1] += xv.y * wv.y; acc[1][2] += xv.y * wv.z; acc[1][3] += xv.y * wv.w;
      acc[2][0] += xv.z * wv.x; acc[2][1] += xv.z * wv.y; acc[2][2] += xv.z * wv.z; acc[2][3] += xv.z * wv.w;
      acc[3][0] += xv.w * wv.x; acc[3][1] += xv.w * wv.y; acc[3][2] += xv.w * wv.z; acc[3][3] += xv.w * wv.w;
    }
  }
  const float* BI = dir ? bib : bif;
  const float* BH = dir ? bhb : bhf;
  float4 b1 = *(const float4*)&BI[r0 + 4 * tidr];
  float4 b2 = *(const float4*)&BH[r0 + 4 * tidr];
  float bx = b1.x + b2.x, by = b1.y + b2.y, bz = b1.z + b2.z, bw = b1.w + b2.w;
  #pragma unroll
  for (int ss = 0; ss < 4; ++ss) {
    int s = s0 + 4 * tids + ss;
    float4 o;
    o.x = acc[ss][0] + bx; o.y = acc[ss][1] + by; o.z = acc[ss][2] + bz; o.w = acc[ss][3] + bw;
    *(float4*)&GX[((size_t)dir * SEQ + s) * G4 + r0 + 4 * tidr] = o;
  }
}

// ---------------------------------------------------------------------------
// K2: persistent BiLSTM, 16-way partition + DOUBLE-BUFFERED tagged-slot
// exchange. grid 32 (= 2 dirs x 16 parts), block 256.
// Reader of step t polls buf[t&1] slot tid until tag==t (data rides in the
// same 8B atom). Publisher writes (h_t, t+1) into buf[(t+1)&1] — which only
// overwrites tag t-1, and a publisher cannot reach tag t+1 before every
// block consumed tag t (its step-t read set includes all blocks' tag-t
// pubs). Max skew = 1 step => equality-poll can never miss. This removes
// R7/R8's latent race (R8 tripwire: lagging block found tag t+1 where it
// needed t -> budget exhaust -> garbage).
// Weights: thread (rr=tid>>2, q=tid&3) owns quarter-row (64 fp32 = 16
// float4), pinned in VGPRs by inline-asm "+v" (defeats L2-restream
// heuristic: R6 VGPR=156, R7 VGPR=104 both refused residency).
// ---------------------------------------------------------------------------
__global__ __launch_bounds__(256, 1) void k_lstm16(
    const float* __restrict__ whf, const float* __restrict__ whb,
    const float* __restrict__ GX, float* __restrict__ H,
    unsigned long long* __restrict__ slot) {
  const int dir = blockIdx.x >> 4;
  const int p   = blockIdx.x & 15;
  const int tid = threadIdx.x;
  const int rr  = tid >> 2;            // local row 0..63
  const int q   = tid & 3;             // k-quarter
  const int gq  = rr >> 4;             // gate of local row
  const int joq = rr & 15;             // local elem of local row
  const int rowQ = (gq << 8) | (p << 4) | joq;      // matvec row
  const int rowC = ((tid >> 4) << 8) | (p << 4) | (tid & 15);  // combine row

  const float4* w4g =
      (const float4*)((dir ? whb : whf) + (size_t)rowQ * HH) + q * 16;
  float4 w[16];
  #pragma unroll
  for (int i = 0; i < 16; ++i) w[i] = w4g[i];
  // Pin weights in VGPRs: opaque to the optimizer, cannot be re-loaded.
  #pragma unroll
  for (int i = 0; i < 16; ++i)
    asm volatile("" : "+v"(w[i].x), "+v"(w[i].y), "+v"(w[i].z), "+v"(w[i].w));

  const float* gxc = GX + (size_t)dir * SEQ * G4 + rowC;  // combine threads
  float* Hd = H + (size_t)dir * HSTR;
  unsigned long long* sl = slot + dir * 512;   // [buf=2][256]

  __shared__ __align__(16) float hl[HH];
  __shared__ float psum[256];
  __shared__ float gacc[64];
  float c = 0.f;                       // valid in tid<16
  int budget = 1 << 18;                // pure failsafe (race now impossible)

  for (int t = 0; t < SEQ; ++t) {
    float gxv = 0.f;
    if (tid < 64) gxv = gxc[(size_t)t * G4];   // pre-poll prefetch (HBM/L2)
    {  // poll own slot in buffer t&1 for h_{t-1}[tid]
      unsigned long long* sp = &sl[(t & 1) * 256 + tid];
      unsigned long long v;
      do {
        v = __hip_atomic_load(sp, __ATOMIC_RELAXED, __HIP_MEMORY_SCOPE_AGENT);
      } while ((unsigned)(v >> 32) != (unsigned)t && --budget > 0);
      union { unsigned u; float f; } cv; cv.u = (unsigned)v;
      hl[tid] = cv.f;
    }
    __syncthreads();
    const float4* h4 = (const float4*)hl + q * 16;
    float a0 = 0.f, a1 = 0.f, a2 = 0.f, a3 = 0.f;
    #pragma unroll
    for (int i = 0; i < 16; ++i) {
      float4 wv = w[i];
      float4 hv = h4[i];
      a0 += wv.x * hv.x; a1 += wv.y * hv.y; a2 += wv.z * hv.z; a3 += wv.w * hv.w;
    }
    psum[tid] = (a0 + a1) + (a2 + a3);
    __syncthreads();
    if (tid < 64) {   // combine quarters + gx for row rowC
      float s = gxv + ((psum[4 * tid] + psum[4 * tid + 1]) +
                       (psum[4 * tid + 2] + psum[4 * tid + 3]));
      gacc[tid] = s;  // layout: gacc[g*16 + jo]
    }
    __syncthreads();
    if (tid < 16) {   // gates, state update, publish (16 owned elements)
      float iv = gacc[tid], fv = gacc[16 + tid], gv = gacc[32 + tid],
            ov = gacc[48 + tid];
      float ig = 1.f / (1.f + expf(-iv));
      float fg = 1.f / (1.f + expf(-fv));
      float gg = tanhf(gv);
      float og = 1.f / (1.f + expf(-ov));
      c = fg * c + ig * gg;
      float h = og * tanhf(c);
      int jj = (p << 4) | tid;
      Hd[(size_t)t * HH + jj] = h;               // plain store for k_feats
      union { float f; unsigned u; } hu; hu.f = h;
      unsigned long long pk =
          ((unsigned long long)(unsigned)(t + 1) << 32) | hu.u;
      __hip_atomic_store(&sl[((t + 1) & 1) * 256 + jj], pk, __ATOMIC_RELAXED,
                         __HIP_MEMORY_SCOPE_AGENT);
    }
  }
}

// ---------------------------------------------------------------------------
// K3: feats = [hf, hb_rev] @ fc_w.T + fc_b.  grid SEQ/16, block 256.
// ---------------------------------------------------------------------------
__global__ __launch_bounds__(256) void k_feats(
    const float* __restrict__ HF, const float* __restrict__ HB,
    const float* __restrict__ fcw, const float* __restrict__ fcb,
    float* __restrict__ FE) {
  __shared__ float hlds[16][512];
  __shared__ float wl[64][65];
  const int tid = threadIdx.x;
  const int s0 = blockIdx.x * 16;
  for (int e = tid; e < 16 * 512; e += 256) {
    int sl = e >> 9, k = e & 511;
    float v = (k < HH) ? HF[(size_t)(s0 + sl) * HH + k]
                       : HB[(size_t)(SEQ - 1 - (s0 + sl)) * HH + (k - HH)];
    hlds[sl][k] = v;
  }
  const int j = tid & 63, sg = tid >> 6;
  float acc[4];
  #pragma unroll
  for (int q = 0; q < 4; ++q) acc[q] = fcb[j];
  for (int kc = 0; kc < 8; ++kc) {
    __syncthreads();
    for (int e = tid; e < 4096; e += 256) {
      int kk = e & 63, jj = e >> 6;
      wl[kk][jj] = fcw[(size_t)jj * 512 + kc * 64 + kk];
    }
    __syncthreads();
    #pragma unroll 8
    for (int kk = 0; kk < 64; ++kk) {
      float wv = wl[kk][j];
      int kg = kc * 64 + kk;
      #pragma unroll
      for (int q = 0; q < 4; ++q) acc[q] += hlds[4 * sg + q][kg] * wv;
    }
  }
  #pragma unroll
  for (int q = 0; q < 4; ++q)
    FE[(size_t)(s0 + 4 * sg + q) * NT + j] = acc[q];
}

// ---------------------------------------------------------------------------
// K4: Viterbi. 1 block x 256 threads (4 waves split the 64-way max).
// numpy-faithful: v = (score[i]+trans[i][j]) + feats[t][j], strict-> first-max.
// ---------------------------------------------------------------------------
__global__ __launch_bounds__(256) void k_viterbi(
    const float* __restrict__ feats, const float* __restrict__ start,
    const float* __restrict__ endv, const float* __restrict__ trans,
    unsigned char* __restrict__ bp, int* __restrict__ out) {
  __shared__ float tr[64 * 64];
  __shared__ float sc[64];
  __shared__ float pval[4][64];
  __shared__ int pidx[4][64];
  const int tid = threadIdx.x;
  for (int e = tid; e < 4096; e += 256) tr[e] = trans[e];
  if (tid < 64) sc[tid] = start[tid] + feats[tid];
  __syncthreads();
  const int w = tid >> 6, j = tid & 63;
  for (int t = 1; t < SEQ; ++t) {
    float fj = feats[t * NT + j];
    float best = -3.0e38f; int bi = 0;
    const int ibase = w << 4;
    #pragma unroll
    for (int ii = 0; ii < 16; ++ii) {
      int i = ibase + ii;
      float v = (sc[i] + tr[(i << 6) | j]) + fj;
      if (v > best) { best = v; bi = i; }
    }
    pval[w][j] = best; pidx[w][j] = bi;
    __syncthreads();
    if (w == 0) {
      float b = pval[0][j]; int x = pidx[0][j];
      if (pval[1][j] > b) { b = pval[1][j]; x = pidx[1][j]; }
      if (pval[2][j] > b) { b = pval[2][j]; x = pidx[2][j]; }
      if (pval[3][j] > b) { b = pval[3][j]; x = pidx[3][j]; }
      bp[t * NT + j] = (unsigned char)x;
      sc[j] = b;
    }
    __syncthreads();
  }
  if (tid == 0) {
    float best = -3.0e38f; int bt = 0;
    for (int i = 0; i < 64; ++i) {
      float v = sc[i] + endv[i];
      if (v > best) { best = v; bt = i; }
    }
    out[SEQ - 1] = bt;
    int tag = bt;
    for (int t = SEQ - 1; t >= 1; --t) {
      tag = bp[t * NT + tag];
      out[t - 1] = tag;
    }
  }
}

// ---------------------------------------------------------------------------
extern "C" void kernel_launch(void* const* d_in, const int* in_sizes, int n_in,
                              void* d_out, int out_size, void* d_ws, size_t ws_size,
                              hipStream_t stream) {
  // --- Defensive guards: any mismatch -> fail visibly (absmax), never fault.
  if (n_in < 19) return;
  if (in_sizes[0] != SEQ || in_sizes[1] != SEQ) return;              // sentence, extra
  if (in_sizes[2] != 1 || in_sizes[3] != 1) return;                  // b, e scalars
  if (in_sizes[4] != 100000 * DE) return;                            // emb
  if (in_sizes[5] != 1000 * DXX) return;                             // extra_emb
  if (in_sizes[6] != G4 * DIN || in_sizes[7] != G4 * HH) return;     // w_ih_f, w_hh_f
  if (in_sizes[8] != G4 || in_sizes[9] != G4) return;                // b_ih_f, b_hh_f
  if (in_sizes[10] != G4 * DIN || in_sizes[11] != G4 * HH) return;   // w_ih_b, w_hh_b
  if (in_sizes[14] != NT * 512 || in_sizes[15] != NT) return;        // fc_w, fc_b
  if (in_sizes[16] != NT || in_sizes[17] != NT) return;              // crf_start, crf_end
  if (in_sizes[18] != NT * NT) return;                               // crf_trans
  if (out_size < SEQ) return;
  if (ws_size < WS_NEEDED_BYTES) return;

  const int*   sent = (const int*)d_in[0];
  const int*   extra = (const int*)d_in[1];
  const float* emb  = (const float*)d_in[4];
  const float* xemb = (const float*)d_in[5];
  const float* wihf = (const float*)d_in[6];
  const float* whhf = (const float*)d_in[7];
  const float* bihf = (const float*)d_in[8];
  const float* bhhf = (const float*)d_in[9];
  const float* wihb = (const float*)d_in[10];
  const float* whhb = (const float*)d_in[11];
  const float* bihb = (const float*)d_in[12];
  const float* bhhb = (const float*)d_in[13];
  const float* fcw  = (const float*)d_in[14];
  const float* fcb  = (const float*)d_in[15];
  const float* cst  = (const float*)d_in[16];
  const float* cen  = (const float*)d_in[17];
  const float* ctr  = (const float*)d_in[18];

  float* ws = (float*)d_ws;
  float* GX = ws + OFF_GX;
  float* H  = ws + OFF_H;
  unsigned long long* SLOT = (unsigned long long*)(ws + OFF_SL);
  float* FE = ws + OFF_FE;
  unsigned char* BP = (unsigned char*)(ws + OFF_BP);

  k_init<<<1, 256, 0, stream>>>(SLOT);
  k_gx<<<dim3(SEQ / 32, G4 / 256, 2), 512, 0, stream>>>(
      sent, extra, emb, xemb, wihf, wihb, bihf, bhhf, bihb, bhhb, GX);
  k_lstm16<<<32, 256, 0, stream>>>(whhf, whhb, GX, H, SLOT);
  k_feats<<<SEQ / 16, 256, 0, stream>>>(H, H + HSTR, fcw, fcb, FE);
  k_viterbi<<<1, 256, 0, stream>>>(FE, cst, cen, ctr, BP, (int*)d_out);
}